// Round 1
// baseline (656.583 us; speedup 1.0000x reference)
//
#include <hip/hip_runtime.h>
#include <math.h>

#define NROWS 65536
#define NDIM  1024
#define NCLS  20

// ---------------------------------------------------------------------------
// Kernel 0: repack W_cls/W_det ([20][1024] each) into d-major Wt[1024][40]
//           (so the 40 weights for one d are contiguous -> s_load friendly),
//           and zero the 20-float column-sum accumulator.
// ---------------------------------------------------------------------------
__global__ __launch_bounds__(256) void repack_w_k(
    const float* __restrict__ Wc, const float* __restrict__ Wd,
    float* __restrict__ Wt, float* __restrict__ colsum)
{
    int i = blockIdx.x * 256 + threadIdx.x;   // exactly 40960 threads
    int d = i / 40;
    int c = i % 40;
    float v = (c < NCLS) ? Wc[c * NDIM + d] : Wd[(c - NCLS) * NDIM + d];
    Wt[i] = v;
    if (i < NCLS) colsum[i] = 0.0f;
}

// ---------------------------------------------------------------------------
// Kernel 1: main fused GEMM + softmax pieces.
//   Block = 256 threads = 4 waves = 2 (row-group) pairs x 2 heads.
//   wave&1==0 -> cls head, wave&1==1 -> det head; lane l owns one row.
//   Each thread computes 20 logits for its (row, head) over K=1024.
//   W comes from SGPRs (wave-uniform address), x via float4 global loads.
//   Epilogue: det wave -> exp + per-class wave reduce + atomicAdd colsum,
//             stores exp(det) to LDS; cls wave -> row softmax, multiplies by
//             twin wave's exp(det), writes pred_cls*exp_det to out.
// ---------------------------------------------------------------------------
__global__ __launch_bounds__(256, 2) void main_gemm_k(
    const float* __restrict__ x,   const float* __restrict__ Wt,
    const float* __restrict__ bc,  const float* __restrict__ bd,
    float* __restrict__ out,       float* __restrict__ colsum)
{
    const int tid  = threadIdx.x;
    const int wave = tid >> 6;
    const int lane = tid & 63;
    const int pair = wave >> 1;       // 0,1 : which 64-row group
    const int h    = wave & 1;        // 0: cls head, 1: det head
    const int hu   = __builtin_amdgcn_readfirstlane(h);   // force wave-uniform

    const int row = blockIdx.x * 128 + pair * 64 + lane;
    const float* __restrict__ xr    = x  + (size_t)row * NDIM;
    const float* __restrict__ wbase = Wt + hu * NCLS;     // uniform

    float acc[NCLS];
#pragma unroll
    for (int c = 0; c < NCLS; ++c) acc[c] = 0.0f;

    // software-pipelined K loop, 16 floats (4x float4) per chunk
    float4 buf[4];
#pragma unroll
    for (int i = 0; i < 4; ++i) buf[i] = ((const float4*)xr)[i];

    for (int d0 = 0; d0 < NDIM; d0 += 16) {
        float4 cur[4];
#pragma unroll
        for (int i = 0; i < 4; ++i) cur[i] = buf[i];
        if (d0 + 16 < NDIM) {
#pragma unroll
            for (int i = 0; i < 4; ++i)
                buf[i] = ((const float4*)(xr + d0 + 16))[i];
        }
        const float* __restrict__ wch = wbase + d0 * 40;  // uniform
#pragma unroll
        for (int dd = 0; dd < 16; ++dd) {
            const float xs = ((const float*)cur)[dd];
            const float* __restrict__ wd = wch + dd * 40; // uniform
#pragma unroll
            for (int c = 0; c < NCLS; ++c)
                acc[c] = fmaf(xs, wd[c], acc[c]);
        }
    }

    __shared__ float e_det[2][64][NCLS];   // 40 KB

    if (h == 1) {
        // ---- det head: exp (no max-subtract; logits are O(±7), safe in fp32)
        float e[NCLS];
#pragma unroll
        for (int c = 0; c < NCLS; ++c) e[c] = expf(acc[c] + bd[c]);
        // per-class wave reduction -> one atomicAdd per class from lane 0
#pragma unroll
        for (int c = 0; c < NCLS; ++c) {
            float v = e[c];
            v += __shfl_xor(v, 32, 64);
            v += __shfl_xor(v, 16, 64);
            v += __shfl_xor(v,  8, 64);
            v += __shfl_xor(v,  4, 64);
            v += __shfl_xor(v,  2, 64);
            v += __shfl_xor(v,  1, 64);
            if (lane == 0) atomicAdd(&colsum[c], v);
        }
#pragma unroll
        for (int c = 0; c < NCLS; ++c) e_det[pair][lane][c] = e[c];
    }
    __syncthreads();
    if (h == 0) {
        // ---- cls head: row softmax over 20 classes
        float l2[NCLS];
        float m = -3.402823466e+38f;
#pragma unroll
        for (int c = 0; c < NCLS; ++c) { l2[c] = acc[c] + bc[c]; m = fmaxf(m, l2[c]); }
        float e[NCLS], s = 0.0f;
#pragma unroll
        for (int c = 0; c < NCLS; ++c) { e[c] = expf(l2[c] - m); s += e[c]; }
        const float inv = 1.0f / s;
        float ov[NCLS];
#pragma unroll
        for (int c = 0; c < NCLS; ++c)
            ov[c] = e[c] * inv * e_det[pair][lane][c];
        float* __restrict__ orow = out + (size_t)row * NCLS;
#pragma unroll
        for (int i = 0; i < 5; ++i)
            ((float4*)orow)[i] = make_float4(ov[4*i], ov[4*i+1], ov[4*i+2], ov[4*i+3]);
    }
}

// ---------------------------------------------------------------------------
// Kernel 2: invert the 20 column sums.
// ---------------------------------------------------------------------------
__global__ void finalize_k(const float* __restrict__ colsum, float* __restrict__ inv)
{
    int c = threadIdx.x;
    if (c < NCLS) inv[c] = 1.0f / colsum[c];
}

// ---------------------------------------------------------------------------
// Kernel 3: scale out[r][c] (= pred_cls * exp_det) by 1/colsum[c].
//   float4 per thread; base = (4i)%20 is a multiple of 4 <= 16, so the four
//   consecutive classes never wrap.
// ---------------------------------------------------------------------------
__global__ __launch_bounds__(256) void scale_k(
    float* __restrict__ out, const float* __restrict__ inv)
{
    int i = blockIdx.x * 256 + threadIdx.x;      // exactly 327680 threads
    int base = (i * 4) % NCLS;
    float4 v = ((float4*)out)[i];
    v.x *= inv[base + 0];
    v.y *= inv[base + 1];
    v.z *= inv[base + 2];
    v.w *= inv[base + 3];
    ((float4*)out)[i] = v;
}

// ---------------------------------------------------------------------------
extern "C" void kernel_launch(void* const* d_in, const int* in_sizes, int n_in,
                              void* d_out, int out_size, void* d_ws, size_t ws_size,
                              hipStream_t stream)
{
    const float* x  = (const float*)d_in[0];
    const float* Wc = (const float*)d_in[1];
    const float* bc = (const float*)d_in[2];
    const float* Wd = (const float*)d_in[3];
    const float* bd = (const float*)d_in[4];
    float* out = (float*)d_out;

    // workspace layout (fp32): Wt[1024*40] | colsum[20] | inv[20]
    float* Wt     = (float*)d_ws;
    float* colsum = Wt + NDIM * 2 * NCLS;
    float* inv    = colsum + NCLS;

    repack_w_k<<<(NDIM * 2 * NCLS) / 256, 256, 0, stream>>>(Wc, Wd, Wt, colsum);
    main_gemm_k<<<NROWS / 128, 256, 0, stream>>>(x, Wt, bc, bd, out, colsum);
    finalize_k<<<1, 64, 0, stream>>>(colsum, inv);
    scale_k<<<(NROWS * NCLS / 4) / 256, 256, 0, stream>>>(out, inv);
}

// Round 11
// 598.744 us; speedup vs baseline: 1.0966x; 1.0966x over previous
//
#include <hip/hip_runtime.h>
#include <math.h>

#define NROWS 65536
#define NDIM  1024
#define NCLS  20
#define NOUT  40     // both heads concatenated: [0,20) cls, [20,40) det
#define KSEG  8
#define KLEN  128    // NDIM / KSEG

// ---------------------------------------------------------------------------
// Kernel 0: repack W_cls/W_det ([20][1024] each) into d-major Wt[1024][40]
//           (40 contiguous floats per d -> s_load_dwordx16 friendly),
//           and zero the 20-float column-sum accumulator.
// ---------------------------------------------------------------------------
__global__ __launch_bounds__(256) void repack_w_k(
    const float* __restrict__ Wc, const float* __restrict__ Wd,
    float* __restrict__ Wt, float* __restrict__ colsum)
{
    int i = blockIdx.x * 256 + threadIdx.x;   // exactly 40960 threads
    int d = i / NOUT;
    int c = i % NOUT;
    float v = (c < NCLS) ? Wc[c * NDIM + d] : Wd[(c - NCLS) * NDIM + d];
    Wt[i] = v;
    if (i < NCLS) colsum[i] = 0.0f;
}

// ---------------------------------------------------------------------------
// Kernel 1: fused dual-head GEMM + softmax pieces, K-split x8 for occupancy.
//   Block = 512 threads = 8 waves. Wave w = K-segment [128w,128w+128);
//   lane = row (64 rows/block). Thread computes 40 partial logits; W comes
//   from SGPRs (wave-uniform address), x via float4 global loads.
//   LDS tree-reduce (conflict-free [40][256] layout, 40KB -> 4 blocks/CU)
//   collapses the 8 K-segments; wave 0 then does the fused epilogue:
//   det exp + per-class wave-reduce + atomicAdd colsum; cls row-softmax;
//   writes pred_cls * exp_det to out.
// ---------------------------------------------------------------------------
__global__ __launch_bounds__(512, 8) void main_gemm_k(
    const float* __restrict__ x,   const float* __restrict__ Wt,
    const float* __restrict__ bc,  const float* __restrict__ bd,
    float* __restrict__ out,       float* __restrict__ colsum)
{
    const int tid  = threadIdx.x;
    const int lane = tid & 63;
    const int w    = tid >> 6;
    const int wu   = __builtin_amdgcn_readfirstlane(w);   // wave-uniform kseg
    const int row  = blockIdx.x * 64 + lane;

    const float* __restrict__ xr   = x  + (size_t)row * NDIM + wu * KLEN;
    const float* __restrict__ wseg = Wt + wu * KLEN * NOUT;          // uniform

    float acc[NOUT];
#pragma unroll
    for (int c = 0; c < NOUT; ++c) acc[c] = 0.0f;

    for (int d0 = 0; d0 < KLEN; d0 += 8) {
        float4 c0 = ((const float4*)(xr + d0))[0];
        float4 c1 = ((const float4*)(xr + d0))[1];
        float cur[8];
        *(float4*)(cur + 0) = c0;
        *(float4*)(cur + 4) = c1;
        const float* __restrict__ wch = wseg + d0 * NOUT;            // uniform
#pragma unroll
        for (int dd = 0; dd < 8; ++dd) {
            const float xs = cur[dd];
#pragma unroll
            for (int c = 0; c < NOUT; ++c)
                acc[c] = fmaf(xs, wch[dd * NOUT + c], acc[c]);
        }
    }

    // ---- LDS tree reduction across the 8 K-segment waves ----
    // Layout [class][slot]: lanes hit consecutive banks -> conflict-free.
    __shared__ float red[NOUT][256];   // 40 KB

    if (w >= 4) {
        const int s = tid - 256;
#pragma unroll
        for (int c = 0; c < NOUT; ++c) red[c][s] = acc[c];
    }
    __syncthreads();
    if (w < 4) {
#pragma unroll
        for (int c = 0; c < NOUT; ++c) acc[c] += red[c][tid];
    }
    __syncthreads();
    if (w == 2 || w == 3) {
        const int s = tid - 128;
#pragma unroll
        for (int c = 0; c < NOUT; ++c) red[c][s] = acc[c];
    }
    __syncthreads();
    if (w < 2) {
#pragma unroll
        for (int c = 0; c < NOUT; ++c) acc[c] += red[c][tid];
    }
    __syncthreads();
    if (w == 1) {
#pragma unroll
        for (int c = 0; c < NOUT; ++c) red[c][tid - 64] = acc[c];
    }
    __syncthreads();

    if (w == 0) {
#pragma unroll
        for (int c = 0; c < NOUT; ++c) acc[c] += red[c][lane];

        // ---- det head: exp in-place (logits are O(+-7), safe without max)
#pragma unroll
        for (int c = 0; c < NCLS; ++c) acc[NCLS + c] = expf(acc[NCLS + c] + bd[c]);

        // per-class wave reduction -> one atomicAdd per class from lane 0
#pragma unroll
        for (int c = 0; c < NCLS; ++c) {
            float v = acc[NCLS + c];
            v += __shfl_xor(v, 32, 64);
            v += __shfl_xor(v, 16, 64);
            v += __shfl_xor(v,  8, 64);
            v += __shfl_xor(v,  4, 64);
            v += __shfl_xor(v,  2, 64);
            v += __shfl_xor(v,  1, 64);
            if (lane == 0) atomicAdd(&colsum[c], v);
        }

        // ---- cls head: row softmax over 20 classes, in-place
        float m = -3.402823466e+38f;
#pragma unroll
        for (int c = 0; c < NCLS; ++c) { acc[c] += bc[c]; m = fmaxf(m, acc[c]); }
        float s = 0.0f;
#pragma unroll
        for (int c = 0; c < NCLS; ++c) { acc[c] = expf(acc[c] - m); s += acc[c]; }
        const float inv = 1.0f / s;

        float* __restrict__ orow = out + (size_t)row * NCLS;
#pragma unroll
        for (int i = 0; i < 5; ++i) {
            float4 v;
            v.x = acc[4*i + 0] * inv * acc[NCLS + 4*i + 0];
            v.y = acc[4*i + 1] * inv * acc[NCLS + 4*i + 1];
            v.z = acc[4*i + 2] * inv * acc[NCLS + 4*i + 2];
            v.w = acc[4*i + 3] * inv * acc[NCLS + 4*i + 3];
            ((float4*)orow)[i] = v;
        }
    }
}

// ---------------------------------------------------------------------------
// Kernel 2: invert the 20 column sums.
// ---------------------------------------------------------------------------
__global__ void finalize_k(const float* __restrict__ colsum, float* __restrict__ inv)
{
    int c = threadIdx.x;
    if (c < NCLS) inv[c] = 1.0f / colsum[c];
}

// ---------------------------------------------------------------------------
// Kernel 3: scale out[r][c] (= pred_cls * exp_det) by 1/colsum[c].
//   float4 per thread; base = (4i)%20 is a multiple of 4 <= 16, never wraps.
// ---------------------------------------------------------------------------
__global__ __launch_bounds__(256) void scale_k(
    float* __restrict__ out, const float* __restrict__ inv)
{
    int i = blockIdx.x * 256 + threadIdx.x;      // exactly 327680 threads
    int base = (i * 4) % NCLS;
    float4 v = ((float4*)out)[i];
    v.x *= inv[base + 0];
    v.y *= inv[base + 1];
    v.z *= inv[base + 2];
    v.w *= inv[base + 3];
    ((float4*)out)[i] = v;
}

// ---------------------------------------------------------------------------
extern "C" void kernel_launch(void* const* d_in, const int* in_sizes, int n_in,
                              void* d_out, int out_size, void* d_ws, size_t ws_size,
                              hipStream_t stream)
{
    const float* x  = (const float*)d_in[0];
    const float* Wc = (const float*)d_in[1];
    const float* bc = (const float*)d_in[2];
    const float* Wd = (const float*)d_in[3];
    const float* bd = (const float*)d_in[4];
    float* out = (float*)d_out;

    // workspace layout (fp32): Wt[1024*40] | colsum[20] | inv[20]
    float* Wt     = (float*)d_ws;
    float* colsum = Wt + NDIM * NOUT;
    float* inv    = colsum + NCLS;

    repack_w_k<<<(NDIM * NOUT) / 256, 256, 0, stream>>>(Wc, Wd, Wt, colsum);
    main_gemm_k<<<NROWS / 64, 512, 0, stream>>>(x, Wt, bc, bd, out, colsum);
    finalize_k<<<1, 64, 0, stream>>>(colsum, inv);
    scale_k<<<(NROWS * NCLS / 4) / 256, 256, 0, stream>>>(out, inv);
}